// Round 10
// baseline (17.614 us; speedup 1.0000x reference)
//
#include <hip/hip_runtime.h>

#define SP 65                 // padded stride
#define A_SZ (64*SP)          // 4160 floats
#define SPL 65
#define NT 512                // 8 waves
#define OMEGA 1.18f           // block-SOR: covers sigma^2<=0.517 (data fit ~0.43),
                              // uniform modulus |lambda|=0.18/sweep (Young 2-cyclic)

// LDS float offsets
#define OFF_G    0
#define OFF_U    (OFF_G + A_SZ)
#define OFF_W    (OFF_U + 128*SPL)
#define OFF_ZM   (OFF_W + 128*SPL)      // [2][64][SP] V_A / V_B mirrors
#define OFF_PR   (OFF_ZM + 2*A_SZ)      // [128] per-line prod
#define OFF_X    (OFF_PR + 128)         // [64] this block's x row
#define OFF_B    (OFF_X + 64)           // [64] bias
#define LDS_FLOATS (OFF_B + 64)         // ~117 KB

// v_mov_dpp with old=0, bound_ctrl -> OOB lanes read 0
template<int CTRL>
__device__ __forceinline__ float dpp0(float v) {
    return __builtin_bit_cast(float,
        __builtin_amdgcn_update_dpp(0, __builtin_bit_cast(int, v), CTRL, 0xF, 0xF, true));
}
__device__ __forceinline__ float rdlane(float v, int l) {
    return __builtin_bit_cast(float, __builtin_amdgcn_readlane(__builtin_bit_cast(int, v), l));
}

struct ScanMasks { float p1, p2, p3, s1, s2, s3; };

// One line's tridiagonal inverse via semiseparable form, register/DPP only:
// z_k = W_k * prefix_{<k}(U*r) + U_k * suffix_{>=k}(W*r)
__device__ __forceinline__ float tri_apply(float r, float su_, float sw_, const ScanMasks& m) {
    float av = su_*r, bv = sw_*r;
    float pa = av;
    pa += dpp0<0x111>(pa);   // row_shr:1
    pa += dpp0<0x112>(pa);   // row_shr:2
    pa += dpp0<0x114>(pa);   // row_shr:4
    pa += dpp0<0x118>(pa);   // row_shr:8
    pa = __fmaf_rn(m.p1, rdlane(pa,15),
         __fmaf_rn(m.p2, rdlane(pa,31),
         __fmaf_rn(m.p3, rdlane(pa,47), pa)));
    float sb = bv;
    sb += dpp0<0x101>(sb);   // row_shl:1
    sb += dpp0<0x102>(sb);   // row_shl:2
    sb += dpp0<0x104>(sb);   // row_shl:4
    sb += dpp0<0x108>(sb);   // row_shl:8
    sb = __fmaf_rn(m.s1, rdlane(sb,16),
         __fmaf_rn(m.s2, rdlane(sb,32),
         __fmaf_rn(m.s3, rdlane(sb,48), sb)));
    return sw_*(pa - av) + su_*sb;
}

// One workgroup per BATCH ROW b (256 blocks, 1/CU). Block-SOR (omega=1.18) on
// the 2-cyclic splitting, exact dense first word-phase V_A^0 = T_r^{-1} b,
// then bit,word,bit,word,final-bit (2.5 sweeps, uniform 0.18 contraction).
// Output via column current conservation:
// out[b][j] = 1000*g_out*V_B[63][j] + bias[j]; final bit phase computes only
// row 63: z_63 = W_63 * prefix_total(U*r).
extern "C" __global__ __launch_bounds__(NT)
void fused_solve(const float* __restrict__ X, const float* __restrict__ Wm,
                 const float* __restrict__ bias, float* __restrict__ out) {
    extern __shared__ float lds[];
    float* Gt = lds + OFF_G;            // Gt[j][i] = W[j][i]*1e-3  (input order)
    float* Ul = lds + OFF_U;
    float* Wl = lds + OFF_W;
    float* zm = lds + OFF_ZM;
    float* pr = lds + OFF_PR;
    float* xs = lds + OFF_X;
    float* bs = lds + OFF_B;

    const int t = threadIdx.x;
    const int wv = t >> 6, lane = t & 63;
    const int b = blockIdx.x;
    const float gl = 0.5f, gin = 0.5f, gout = 0.5f, c2 = 0.25f;

    // ---- stage conductances (coalesced), x row, bias ----
    for (int s = t; s < 4096; s += NT) {
        int j = s >> 6, i = s & 63;
        Gt[j*SP + i] = Wm[s] * 1e-3f;
    }
    if (t < 64) xs[t] = X[b*64 + t];
    else if (t < 128) bs[t-64] = bias[t-64];
    __syncthreads();

    // ---- factorization: forward (t<128) and backward (128<=t<256) concurrent ----
    if (t < 128) {                       // forward: d-recurrence -> Ul, prod
        const int line = t; const bool word = line < 64; const int lc = word ? line : line - 64;
        float Ui = 1.0f, prod = 1.0f, rdprev = 0.f;
        for (int k = 0; k < 64; ++k) {
            float g = word ? Gt[k*SP + lc] : Gt[lc*SP + k];
            float bb = g + gl*((k>0)+(k<63)) + (word ? (k==0?gin:0.f) : (k==63?gout:0.f));
            float d = bb - c2*rdprev;
            Ul[line*SPL + k] = Ui;
            float rd = __builtin_amdgcn_rcpf(d);
            Ui   *= d*2.0f;              // *= d/gl
            prod *= 0.5f*rd;             // *= gl/d
            rdprev = rd;
        }
        pr[line] = prod;
    } else if (t < 256) {                // backward: e-recurrence -> W' (unscaled)
        const int line = t - 128; const bool word = line < 64; const int lc = word ? line : line - 64;
        float Wj = 2.0f, eprev = 0.f;    // W'_63 = 1/gl
        for (int k = 63; k >= 0; --k) {
            float g = word ? Gt[k*SP + lc] : Gt[lc*SP + k];
            float bb = g + gl*((k>0)+(k<63)) + (word ? (k==0?gin:0.f) : (k==63?gout:0.f));
            if (k == 63) { Wl[line*SPL + 63] = Wj; eprev = bb; }
            else {
                Wj *= eprev*2.0f;        // *= e/gl
                Wl[line*SPL + k] = Wj;
                eprev = bb - c2*__builtin_amdgcn_rcpf(eprev);
            }
        }
    }
    __syncthreads();

    // ---- preload per-line coefficients: 8 word + 8 bit lines per wave ----
    float su[16], swt[16], gsg[16], xr[8], va[8], vb[8];
    #pragma unroll
    for (int li = 0; li < 8; ++li) {
        const int L = wv*8 + li;
        su[li]    = Ul[L*SPL + lane];
        swt[li]   = Wl[L*SPL + lane] * pr[L];
        gsg[li]   = Gt[lane*SP + L];                    // word line i=L, j=lane
        su[8+li]  = Ul[(64+L)*SPL + lane];
        swt[8+li] = Wl[(64+L)*SPL + lane] * pr[64+L];
        gsg[8+li] = Gt[L*SP + lane];                    // bit line j=L, i=lane
        xr[li]    = gin * xs[L];
    }

    // ---- exact init: V_A^0[i][j] = g_in*x_i * U_0 W_j = xr*swt ----
    #pragma unroll
    for (int li = 0; li < 8; ++li) {
        const int L = wv*8 + li;
        va[li] = xr[li] * swt[li];
        vb[li] = 0.f;
        zm[L*SP + lane] = va[li];
    }
    __syncthreads();

    const int rrow = lane >> 4;
    ScanMasks m;
    m.p1 = rrow >= 1 ? 1.f : 0.f;  m.p2 = rrow >= 2 ? 1.f : 0.f;  m.p3 = rrow >= 3 ? 1.f : 0.f;
    m.s1 = rrow <  1 ? 1.f : 0.f;  m.s2 = rrow <  2 ? 1.f : 0.f;  m.s3 = rrow <  3 ? 1.f : 0.f;

    // ---- 2 full SOR sweeps (bit, word) ----
    #pragma unroll 1
    for (int sw = 0; sw < 2; ++sw) {
        #pragma unroll
        for (int li = 0; li < 8; ++li) {            // bit phase
            const int L = wv*8 + li;
            float rhs = gsg[8+li] * zm[lane*SP + L];
            float tri = tri_apply(rhs, su[8+li], swt[8+li], m);
            vb[li] = (1.f-OMEGA)*vb[li] + OMEGA*tri;
            zm[A_SZ + lane*SP + L] = vb[li];
        }
        __syncthreads();
        #pragma unroll
        for (int li = 0; li < 8; ++li) {            // word phase
            const int L = wv*8 + li;
            float rhs = gsg[li] * zm[A_SZ + L*SP + lane];
            if (lane == 0) rhs += xr[li];
            float tri = tri_apply(rhs, su[li], swt[li], m);
            va[li] = (1.f-OMEGA)*va[li] + OMEGA*tri;
            zm[L*SP + lane] = va[li];
        }
        __syncthreads();
    }

    // ---- final bit phase: only row 63 needed; z_63 = W_63 * prefix_total(U*r) ----
    #pragma unroll
    for (int li = 0; li < 8; ++li) {
        const int L = wv*8 + li;
        float rhs = gsg[8+li] * zm[lane*SP + L];
        float pa = su[8+li]*rhs;
        pa += dpp0<0x111>(pa);
        pa += dpp0<0x112>(pa);
        pa += dpp0<0x114>(pa);
        pa += dpp0<0x118>(pa);
        pa = __fmaf_rn(m.p1, rdlane(pa,15),
             __fmaf_rn(m.p2, rdlane(pa,31),
             __fmaf_rn(m.p3, rdlane(pa,47), pa)));
        // at lane 63: pa = inclusive prefix total = sum_k U_k r_k
        float tri63 = swt[8+li] * pa;
        float vbn = (1.f-OMEGA)*vb[li] + OMEGA*tri63;
        if (lane == 63)
            out[b*64 + L] = 1000.0f * gout * vbn + bs[L];
    }
}

extern "C" void kernel_launch(void* const* d_in, const int* in_sizes, int n_in,
                              void* d_out, int out_size, void* d_ws, size_t ws_size,
                              hipStream_t stream) {
    const float* x    = (const float*)d_in[0];
    const float* w    = (const float*)d_in[1];
    const float* bias = (const float*)d_in[2];
    float* out  = (float*)d_out;

    size_t lds_bytes = (size_t)LDS_FLOATS * sizeof(float);
    hipFuncSetAttribute((const void*)fused_solve,
                        hipFuncAttributeMaxDynamicSharedMemorySize, (int)lds_bytes);

    fused_solve<<<256, NT, lds_bytes, stream>>>(x, w, bias, out);
}

// Round 11
// 17.559 us; speedup vs baseline: 1.0031x; 1.0031x over previous
//
#include <hip/hip_runtime.h>

#define SP 65                 // padded stride for zm
#define A_SZ (64*SP)          // 4160 floats
#define SPL 65                // stride for Ul/Wl line tables
#define GSP 68                // stride for Gt (16B-aligned rows for float4 staging)
#define NT 512                // 8 waves
#define OMEGA 1.18f           // block-SOR: covers sigma^2<=0.517 (data fit ~0.43-0.47),
                              // uniform modulus |lambda|=0.18/sweep (Young 2-cyclic)

// LDS float offsets
#define OFF_G    0
#define OFF_U    (OFF_G + 64*GSP)       // 4352
#define OFF_W    (OFF_U + 128*SPL)
#define OFF_ZM   (OFF_W + 128*SPL)      // [2][64][SP] V_A / V_B mirrors
#define OFF_PR   (OFF_ZM + 2*A_SZ)      // [128] per-line prod
#define OFF_X    (OFF_PR + 128)         // [64] this block's x row
#define OFF_B    (OFF_X + 64)           // [64] bias
#define LDS_FLOATS (OFF_B + 64)         // ~115.6 KB

// v_mov_dpp with old=0, bound_ctrl -> OOB lanes read 0
template<int CTRL>
__device__ __forceinline__ float dpp0(float v) {
    return __builtin_bit_cast(float,
        __builtin_amdgcn_update_dpp(0, __builtin_bit_cast(int, v), CTRL, 0xF, 0xF, true));
}
__device__ __forceinline__ float rdlane(float v, int l) {
    return __builtin_bit_cast(float, __builtin_amdgcn_readlane(__builtin_bit_cast(int, v), l));
}

struct ScanMasks { float p1, p2, p3, s1, s2, s3; };

// One line's tridiagonal inverse via semiseparable form, register/DPP only:
// z_k = W_k * prefix_{<k}(U*r) + U_k * suffix_{>=k}(W*r)
__device__ __forceinline__ float tri_apply(float r, float su_, float sw_, const ScanMasks& m) {
    float av = su_*r, bv = sw_*r;
    float pa = av;
    pa += dpp0<0x111>(pa);   // row_shr:1
    pa += dpp0<0x112>(pa);   // row_shr:2
    pa += dpp0<0x114>(pa);   // row_shr:4
    pa += dpp0<0x118>(pa);   // row_shr:8
    pa = __fmaf_rn(m.p1, rdlane(pa,15),
         __fmaf_rn(m.p2, rdlane(pa,31),
         __fmaf_rn(m.p3, rdlane(pa,47), pa)));
    float sb = bv;
    sb += dpp0<0x101>(sb);   // row_shl:1
    sb += dpp0<0x102>(sb);   // row_shl:2
    sb += dpp0<0x104>(sb);   // row_shl:4
    sb += dpp0<0x108>(sb);   // row_shl:8
    sb = __fmaf_rn(m.s1, rdlane(sb,16),
         __fmaf_rn(m.s2, rdlane(sb,32),
         __fmaf_rn(m.s3, rdlane(sb,48), sb)));
    return sw_*(pa - av) + su_*sb;
}

// One workgroup per BATCH ROW b (256 blocks, 1/CU). Block-SOR (omega=1.18) on
// the 2-cyclic splitting. Phases: BIT1 (reads analytic V_A^0 = gin*x_i*W_j*pr_i
// straight from the factor tables -- no init materialization), WORD, BIT,
// WORD, FINAL-BIT (row 63 only, prefix half). 6 barriers total.
// Output via column current conservation: out[b][j] = 1000*g_out*V_B[63][j]+bias[j].
extern "C" __global__ __launch_bounds__(NT)
void fused_solve(const float* __restrict__ X, const float* __restrict__ Wm,
                 const float* __restrict__ bias, float* __restrict__ out) {
    extern __shared__ float lds[];
    float* Gt = lds + OFF_G;            // Gt[j][i] = W[j][i]*1e-3  (input order)
    float* Ul = lds + OFF_U;
    float* Wl = lds + OFF_W;
    float* zm = lds + OFF_ZM;
    float* pr = lds + OFF_PR;
    float* xs = lds + OFF_X;
    float* bs = lds + OFF_B;

    const int t = threadIdx.x;
    const int wv = t >> 6, lane = t & 63;
    const int b = blockIdx.x;
    const float gl = 0.5f, gin = 0.5f, gout = 0.5f, c2 = 0.25f;

    // ---- stage conductances (float4, coalesced), x row, bias ----
    for (int s = t; s < 1024; s += NT) {
        int row = s >> 4, col = (s & 15) * 4;
        float4 v = *(const float4*)&Wm[row*64 + col];
        v.x *= 1e-3f; v.y *= 1e-3f; v.z *= 1e-3f; v.w *= 1e-3f;
        *(float4*)&Gt[row*GSP + col] = v;
    }
    if (t < 64) xs[t] = X[b*64 + t];
    else if (t < 128) bs[t-64] = bias[t-64];
    __syncthreads();

    // ---- factorization: forward (t<128) and backward (128<=t<256) concurrent ----
    if (t < 128) {                       // forward: d-recurrence -> Ul, prod
        const int line = t; const bool word = line < 64; const int lc = word ? line : line - 64;
        float Ui = 1.0f, prod = 1.0f, rdprev = 0.f;
        for (int k = 0; k < 64; ++k) {
            float g = word ? Gt[k*GSP + lc] : Gt[lc*GSP + k];
            float bb = g + gl*((k>0)+(k<63)) + (word ? (k==0?gin:0.f) : (k==63?gout:0.f));
            float d = bb - c2*rdprev;
            Ul[line*SPL + k] = Ui;
            float rd = __builtin_amdgcn_rcpf(d);
            Ui   *= d*2.0f;              // *= d/gl
            prod *= 0.5f*rd;             // *= gl/d
            rdprev = rd;
        }
        pr[line] = prod;
    } else if (t < 256) {                // backward: e-recurrence -> W' (unscaled)
        const int line = t - 128; const bool word = line < 64; const int lc = word ? line : line - 64;
        float Wj = 2.0f, eprev = 0.f;    // W'_63 = 1/gl
        for (int k = 63; k >= 0; --k) {
            float g = word ? Gt[k*GSP + lc] : Gt[lc*GSP + k];
            float bb = g + gl*((k>0)+(k<63)) + (word ? (k==0?gin:0.f) : (k==63?gout:0.f));
            if (k == 63) { Wl[line*SPL + 63] = Wj; eprev = bb; }
            else {
                Wj *= eprev*2.0f;        // *= e/gl
                Wl[line*SPL + k] = Wj;
                eprev = bb - c2*__builtin_amdgcn_rcpf(eprev);
            }
        }
    }
    __syncthreads();

    // ---- preload per-line coefficients: 8 word + 8 bit lines per wave ----
    float su[16], swt[16], gsg[16], xr[8], va[8], vb[8];
    #pragma unroll
    for (int li = 0; li < 8; ++li) {
        const int L = wv*8 + li;
        su[li]    = Ul[L*SPL + lane];
        swt[li]   = Wl[L*SPL + lane] * pr[L];
        gsg[li]   = Gt[lane*GSP + L];                   // word line i=L, j=lane
        su[8+li]  = Ul[(64+L)*SPL + lane];
        swt[8+li] = Wl[(64+L)*SPL + lane] * pr[64+L];
        gsg[8+li] = Gt[L*GSP + lane];                   // bit line j=L, i=lane
        xr[li]    = gin * xs[L];
        va[li]    = xr[li] * swt[li];                   // V_A^0 (register copy)
    }
    // per-thread factor for reading V_A^0 transposed: V_A^0[lane][j] = xp * Wl[lane][j]
    const float xp = gin * xs[lane] * pr[lane];

    const int rrow = lane >> 4;
    ScanMasks m;
    m.p1 = rrow >= 1 ? 1.f : 0.f;  m.p2 = rrow >= 2 ? 1.f : 0.f;  m.p3 = rrow >= 3 ? 1.f : 0.f;
    m.s1 = rrow <  1 ? 1.f : 0.f;  m.s2 = rrow <  2 ? 1.f : 0.f;  m.s3 = rrow <  3 ? 1.f : 0.f;

    // ---- BIT1: rhs from analytic V_A^0 (no materialized init phase) ----
    #pragma unroll
    for (int li = 0; li < 8; ++li) {
        const int L = wv*8 + li;
        float rhs = gsg[8+li] * (xp * Wl[lane*SPL + L]);
        float tri = tri_apply(rhs, su[8+li], swt[8+li], m);
        vb[li] = OMEGA*tri;                             // vb^0 = 0
        zm[A_SZ + lane*SP + L] = vb[li];
    }
    __syncthreads();

    // ---- WORD1 ----
    #pragma unroll
    for (int li = 0; li < 8; ++li) {
        const int L = wv*8 + li;
        float rhs = gsg[li] * zm[A_SZ + L*SP + lane];
        if (lane == 0) rhs += xr[li];
        float tri = tri_apply(rhs, su[li], swt[li], m);
        va[li] = (1.f-OMEGA)*va[li] + OMEGA*tri;
        zm[L*SP + lane] = va[li];
    }
    __syncthreads();

    // ---- BIT2 ----
    #pragma unroll
    for (int li = 0; li < 8; ++li) {
        const int L = wv*8 + li;
        float rhs = gsg[8+li] * zm[lane*SP + L];
        float tri = tri_apply(rhs, su[8+li], swt[8+li], m);
        vb[li] = (1.f-OMEGA)*vb[li] + OMEGA*tri;
        zm[A_SZ + lane*SP + L] = vb[li];
    }
    __syncthreads();

    // ---- WORD2 ----
    #pragma unroll
    for (int li = 0; li < 8; ++li) {
        const int L = wv*8 + li;
        float rhs = gsg[li] * zm[A_SZ + L*SP + lane];
        if (lane == 0) rhs += xr[li];
        float tri = tri_apply(rhs, su[li], swt[li], m);
        va[li] = (1.f-OMEGA)*va[li] + OMEGA*tri;
        zm[L*SP + lane] = va[li];
    }
    __syncthreads();

    // ---- FINAL BIT: only row 63 needed; z_63 = W_63 * prefix_total(U*r) ----
    #pragma unroll
    for (int li = 0; li < 8; ++li) {
        const int L = wv*8 + li;
        float rhs = gsg[8+li] * zm[lane*SP + L];
        float pa = su[8+li]*rhs;
        pa += dpp0<0x111>(pa);
        pa += dpp0<0x112>(pa);
        pa += dpp0<0x114>(pa);
        pa += dpp0<0x118>(pa);
        pa = __fmaf_rn(m.p1, rdlane(pa,15),
             __fmaf_rn(m.p2, rdlane(pa,31),
             __fmaf_rn(m.p3, rdlane(pa,47), pa)));
        // at lane 63: pa = inclusive prefix total = sum_k U_k r_k
        float tri63 = swt[8+li] * pa;
        float vbn = (1.f-OMEGA)*vb[li] + OMEGA*tri63;
        if (lane == 63)
            out[b*64 + L] = 1000.0f * gout * vbn + bs[L];
    }
}

extern "C" void kernel_launch(void* const* d_in, const int* in_sizes, int n_in,
                              void* d_out, int out_size, void* d_ws, size_t ws_size,
                              hipStream_t stream) {
    const float* x    = (const float*)d_in[0];
    const float* w    = (const float*)d_in[1];
    const float* bias = (const float*)d_in[2];
    float* out  = (float*)d_out;

    size_t lds_bytes = (size_t)LDS_FLOATS * sizeof(float);
    hipFuncSetAttribute((const void*)fused_solve,
                        hipFuncAttributeMaxDynamicSharedMemorySize, (int)lds_bytes);

    fused_solve<<<256, NT, lds_bytes, stream>>>(x, w, bias, out);
}